// Round 4
// baseline (642.731 us; speedup 1.0000x reference)
//
#include <hip/hip_runtime.h>

#define SEQ   16384
#define DIM   2048
#define CHUNK 64
#define NCHUNK (SEQ / CHUNK)   // 256

typedef __attribute__((ext_vector_type(8))) short  short8;
typedef __attribute__((ext_vector_type(4))) short  short4v;
typedef __attribute__((ext_vector_type(4))) float  floatx4;

static __device__ __forceinline__ float bf2f(short s) {
    return __uint_as_float(((unsigned)(unsigned short)s) << 16);
}
static __device__ __forceinline__ short f2bf(float f) {
    unsigned u = __float_as_uint(f);
    u += 0x7fff + ((u >> 16) & 1);   // RNE
    return (short)(u >> 16);
}

// ---------- fp32 -> bf16 cast, float4 vectorized ----------
__global__ void cast_kernel(const float* __restrict__ in, short* __restrict__ out, int n4) {
    int i = blockIdx.x * blockDim.x + threadIdx.x;
    if (i >= n4) return;
    float4 v = ((const float4*)in)[i];
    short4v s;
    s.x = f2bf(v.x); s.y = f2bf(v.y); s.z = f2bf(v.z); s.w = f2bf(v.w);
    ((short4v*)out)[i] = s;
}

// ---------- bf16 GEMM, C[m][n] = sum_k A[m][k]*B[n][k] (both K-contiguous) ----------
// 256x256 tile, BK=64, 512 threads = 8 waves (2M x 4N), wave => contiguous 128x64
// output (rows wrow*128.., cols wcol*64..). B-IN-REGISTERS schedule (m201 read
// economy): at each K-tile's first phase the wave reads ALL its B fragments
// (8 b128, resident 4 phases) + A-groups g0,g1; later phases read ONE 4-read
// A-group, one phase ahead of its MFMA. Per-phase: 16 MFMA vs 4-16 ds_reads.
// Stage slots per region lifetime; vmcnt(4) at P4/P8 only (counted, never 0).
// XOR-8 slot swizzle both-sides (bank-conflict-free, verified 0).
// FUSE==0: store bf16 C. FUSE==1: store fp32 C + xs*dskip.

#define BAR   __builtin_amdgcn_s_barrier()
#define PRIO1 __builtin_amdgcn_s_setprio(1)
#define PRIO0 __builtin_amdgcn_s_setprio(0)
#define VMC4  asm volatile("s_waitcnt vmcnt(4)" ::: "memory")
#define VMC0  asm volatile("s_waitcnt vmcnt(0)" ::: "memory")

// stage one 128x64 half-tile (16 KiB): 2 x global_load_lds(16B) per thread.
// LDS dest linear; global source slot XOR-swizzled (involution s^(row&7)).
#define STAGE_A(b, h, t) do { \
    const short* _s = Abase + (size_t)(h) * 128 * K + (size_t)(t) * 64; \
    __builtin_amdgcn_global_load_lds(_s + gOff0, &As[b][h][c0 * 8], 16, 0, 0); \
    __builtin_amdgcn_global_load_lds(_s + gOff1, &As[b][h][c1 * 8], 16, 0, 0); \
} while (0)
#define STAGE_B(b, h, t) do { \
    const short* _s = Bbase + (size_t)(h) * 128 * K + (size_t)(t) * 64; \
    __builtin_amdgcn_global_load_lds(_s + gOff0, &Bs[b][h][c0 * 8], 16, 0, 0); \
    __builtin_amdgcn_global_load_lds(_s + gOff1, &Bs[b][h][c1 * 8], 16, 0, 0); \
} while (0)

// fragment reads: logical slot (ks*4+quad), physical slot XOR (lrow&7) = sx
#define READ_A(dst, b, g) \
    _Pragma("unroll") \
    for (int ml = 0; ml < 2; ml++) { \
        _Pragma("unroll") \
        for (int ks = 0; ks < 2; ks++) \
            dst[ml][ks] = *(const short8*)&As[b][wrow][((g) * 32 + ml * 16 + l16) * 64 + \
                                                       ((((ks << 2) | quad) ^ sx) << 3)]; \
    }
#define READ_B(b) \
    _Pragma("unroll") \
    for (int ni = 0; ni < 4; ni++) { \
        _Pragma("unroll") \
        for (int ks = 0; ks < 2; ks++) \
            bR[ni][ks] = *(const short8*)&Bs[b][bhalf][(brow0 + ni * 16) * 64 + \
                                                       ((((ks << 2) | quad) ^ sx) << 3)]; \
    }
// one phase's MFMA: A-group g (2 mi) x all 4 ni x 2 ks = 16 MFMA
#define MMA_G(g, aS) \
    _Pragma("unroll") \
    for (int ml = 0; ml < 2; ml++) { \
        _Pragma("unroll") \
        for (int ni = 0; ni < 4; ni++) { \
            acc[(g) * 2 + ml][ni] = __builtin_amdgcn_mfma_f32_16x16x32_bf16( \
                aS[ml][0], bR[ni][0], acc[(g) * 2 + ml][ni], 0, 0, 0); \
            acc[(g) * 2 + ml][ni] = __builtin_amdgcn_mfma_f32_16x16x32_bf16( \
                aS[ml][1], bR[ni][1], acc[(g) * 2 + ml][ni], 0, 0, 0); \
        } \
    }

template<int FUSE>
__global__ __launch_bounds__(512, 2)
void gemm_bt(const short* __restrict__ A, const short* __restrict__ B,
             short* __restrict__ Cbf, float* __restrict__ Cf,
             const float* __restrict__ xs, const float* __restrict__ dskip)
{
    constexpr int K  = DIM;        // 2048
    constexpr int NT = K / 64;     // 32 K-tiles

    __shared__ alignas(16) short As[2][2][128 * 64];   // [buf][half][row*64+slot*8]
    __shared__ alignas(16) short Bs[2][2][128 * 64];

    const int tid = threadIdx.x;
    const int m0  = blockIdx.y * 256;
    const int n0  = blockIdx.x * 256;   // gridDim.x==8 == NXCD: one B-panel per XCD

    const int lane = tid & 63;
    const int wv   = tid >> 6;
    const int wrow = wv >> 2;           // 0..1  (A half = wrow)
    const int wcol = wv & 3;            // 0..3
    const int l16  = lane & 15;
    const int quad = lane >> 4;
    const int sx   = l16 & 7;
    const int bhalf = wcol >> 1;
    const int brow0 = (wcol & 1) * 64 + l16;

    // staging constants: chunks c0, c1 of each half-tile (1024 x 16B chunks)
    const int c0 = tid, c1 = tid + 512;
    const int r0 = c0 >> 3, r1 = c1 >> 3;
    const size_t gOff0 = (size_t)r0 * K + (size_t)((((c0 & 7) ^ (r0 & 7))) * 8);
    const size_t gOff1 = (size_t)r1 * K + (size_t)((((c1 & 7) ^ (r1 & 7))) * 8);
    const short* Abase = A + (size_t)m0 * K;
    const short* Bbase = B + (size_t)n0 * K;

    short8  bR[4][2], aE[2][2], aO[2][2];
    floatx4 acc[8][4] = {};            // [mi][ni]

    // ---- prologue: buf0 <- t0 (8 loads); B1 <- t1 (4 loads). vmcnt(4) leaves B1.
    STAGE_A(0, 0, 0); STAGE_A(0, 1, 0); STAGE_B(0, 0, 0); STAGE_B(0, 1, 0);
    STAGE_B(1, 0, 1); STAGE_B(1, 1, 1);
    VMC4;
    BAR;

    #pragma unroll 1
    for (int i = 0; i < NT / 2; ++i) {
        const int t1 = 2 * i + 1;
        const int t2 = (2 * i + 2) & (NT - 1);   // wrap: tail stages harmless
        const int t3 = (2 * i + 3) & (NT - 1);

        // ================= tile even (buf0) =================
        // P1: read all B + A-g0,g1 (16 reads); stage A1h0+A1h1 <- t1; mma g0
        READ_B(0); READ_A(aE, 0, 0); READ_A(aO, 0, 1);
        STAGE_A(1, 0, t1); STAGE_A(1, 1, t1);
        PRIO1; MMA_G(0, aE); PRIO0;
        BAR;
        // P2: read A-g2; stage B0h0 <- t2; mma g1
        READ_A(aE, 0, 2); STAGE_B(0, 0, t2);
        PRIO1; MMA_G(1, aO); PRIO0;
        BAR;
        // P3: read A-g3; stage B0h1 <- t2; mma g2
        READ_A(aO, 0, 3); STAGE_B(0, 1, t2);
        PRIO1; MMA_G(2, aE); PRIO0;
        BAR;
        // P4: mma g3; vmcnt(4) drains prevP7/P8 (B1) + P1 (A1) => buf1 ready
        PRIO1; MMA_G(3, aO); PRIO0;
        VMC4;
        BAR;

        // ================= tile odd (buf1) =================
        // P5: read all B + A-g0,g1; stage A0h0 <- t2; mma g0
        READ_B(1); READ_A(aE, 1, 0); READ_A(aO, 1, 1);
        STAGE_A(0, 0, t2);
        PRIO1; MMA_G(0, aE); PRIO0;
        BAR;
        // P6: read A-g2; stage A0h1 <- t2; mma g1
        READ_A(aE, 1, 2); STAGE_A(0, 1, t2);
        PRIO1; MMA_G(1, aO); PRIO0;
        BAR;
        // P7: read A-g3; stage B1h0 <- t3; mma g2
        READ_A(aO, 1, 3); STAGE_B(1, 0, t3);
        PRIO1; MMA_G(2, aE); PRIO0;
        BAR;
        // P8: stage B1h1 <- t3; mma g3; vmcnt(4) drains P2,P3(B0)+P5,P6(A0) => buf0 ready
        STAGE_B(1, 1, t3);
        PRIO1; MMA_G(3, aO); PRIO0;
        VMC4;
        BAR;
    }
    VMC0;   // no LDS-DMA may outlive this workgroup

    // ---- epilogue: row = m0 + wrow*128 + mi*16 + quad*4 + r; col = n0 + wcol*64 + ni*16 + l16
    if (FUSE == 0) {
        #pragma unroll
        for (int mi = 0; mi < 8; mi++) {
            const int rb = m0 + wrow * 128 + mi * 16 + quad * 4;
            #pragma unroll
            for (int ni = 0; ni < 4; ni++) {
                const int cc = n0 + wcol * 64 + ni * 16 + l16;
                #pragma unroll
                for (int r = 0; r < 4; r++)
                    Cbf[(size_t)(rb + r) * DIM + cc] = f2bf(acc[mi][ni][r]);
            }
        }
    } else {
        float dsk[4];
        #pragma unroll
        for (int ni = 0; ni < 4; ni++) dsk[ni] = dskip[n0 + wcol * 64 + ni * 16 + l16];
        #pragma unroll
        for (int mi = 0; mi < 8; mi++) {
            const int rb = m0 + wrow * 128 + mi * 16 + quad * 4;
            #pragma unroll
            for (int ni = 0; ni < 4; ni++) {
                const int cc = n0 + wcol * 64 + ni * 16 + l16;
                #pragma unroll
                for (int r = 0; r < 4; r++) {
                    size_t idx = (size_t)(rb + r) * DIM + cc;
                    Cf[idx] = acc[mi][ni][r] + xs[idx] * dsk[ni];
                }
            }
        }
    }
}

// ---------- scan pass 1: per-chunk local final state (zero init), 4 cols/thread ----------
__global__ void scan_pass1(const short* __restrict__ bx, const float* __restrict__ lam,
                           float* __restrict__ blockLast)
{
    int q     = blockIdx.x * 256 + threadIdx.x;   // 4-col group id, q < DIM/4
    int n     = q * 4;
    int chunk = blockIdx.y;
    float4 lm = *(const float4*)&lam[n];
    const uint2* p = (const uint2*)(bx + (size_t)chunk * CHUNK * DIM) + q;
    float h0 = 0.f, h1 = 0.f, h2 = 0.f, h3 = 0.f;
    #pragma unroll 16
    for (int i = 0; i < CHUNK; i++) {
        uint2 v = p[(size_t)i * (DIM / 4)];
        h0 = fmaf(lm.x, h0, bf2f((short)(v.x & 0xffffu)));
        h1 = fmaf(lm.y, h1, bf2f((short)(v.x >> 16)));
        h2 = fmaf(lm.z, h2, bf2f((short)(v.y & 0xffffu)));
        h3 = fmaf(lm.w, h3, bf2f((short)(v.y >> 16)));
    }
    float4 o; o.x = h0; o.y = h1; o.z = h2; o.w = h3;
    *(float4*)&blockLast[(size_t)chunk * DIM + n] = o;
}

// ---------- scan pass 2: exclusive prefix over chunks (in place), 1 col/thread ----------
__global__ void scan_pass2(float* __restrict__ blockLast, const float* __restrict__ lam)
{
    int n = blockIdx.x * 256 + threadIdx.x;
    float lm = lam[n];
    float p = lm;
    #pragma unroll
    for (int i = 0; i < 6; i++) p = p * p;    // lam^64
    float carry = 0.f;
    #pragma unroll 4
    for (int c = 0; c < NCHUNK; c++) {
        float t = blockLast[(size_t)c * DIM + n];
        blockLast[(size_t)c * DIM + n] = carry;
        carry = fmaf(p, carry, t);
    }
}

// ---------- scan pass 3: apply carry, write hs (bf16, in place over bx), 4 cols/thread ----------
__global__ void scan_pass3(short* __restrict__ bxh, const float* __restrict__ lam,
                           const float* __restrict__ carry)
{
    int q     = blockIdx.x * 256 + threadIdx.x;
    int n     = q * 4;
    int chunk = blockIdx.y;
    float4 lm = *(const float4*)&lam[n];
    float4 cv = *(const float4*)&carry[(size_t)chunk * DIM + n];
    float h0 = cv.x, h1 = cv.y, h2 = cv.z, h3 = cv.w;
    uint2* p = (uint2*)(bxh + (size_t)chunk * CHUNK * DIM) + q;
    #pragma unroll 16
    for (int i = 0; i < CHUNK; i++) {
        uint2 v = p[(size_t)i * (DIM / 4)];
        h0 = fmaf(lm.x, h0, bf2f((short)(v.x & 0xffffu)));
        h1 = fmaf(lm.y, h1, bf2f((short)(v.x >> 16)));
        h2 = fmaf(lm.z, h2, bf2f((short)(v.y & 0xffffu)));
        h3 = fmaf(lm.w, h3, bf2f((short)(v.y >> 16)));
        uint2 o;
        o.x = (unsigned)(unsigned short)f2bf(h0) | ((unsigned)(unsigned short)f2bf(h1) << 16);
        o.y = (unsigned)(unsigned short)f2bf(h2) | ((unsigned)(unsigned short)f2bf(h3) << 16);
        p[(size_t)i * (DIM / 4)] = o;
    }
}

extern "C" void kernel_launch(void* const* d_in, const int* in_sizes, int n_in,
                              void* d_out, int out_size, void* d_ws, size_t ws_size,
                              hipStream_t stream)
{
    const float* xs    = (const float*)d_in[0];
    const float* lam   = (const float*)d_in[1];
    const float* w_in  = (const float*)d_in[2];
    const float* c_out = (const float*)d_in[3];
    const float* dskip = (const float*)d_in[4];
    float* out = (float*)d_out;

    // ws layout:
    //   [0,   64M) : bx / hs  bf16  [SEQ][DIM]
    //   [64M, 72M) : w_in     bf16  [DIM][DIM]
    //   [72M, 80M) : c_out    bf16  [DIM][DIM]
    char*  ws    = (char*)d_ws;
    short* bxh   = (short*)ws;
    short* w_bf  = (short*)(ws + (size_t)64 * 1024 * 1024);
    short* c_bf  = (short*)(ws + (size_t)72 * 1024 * 1024);
    // xs_bf16 in front 64 MiB of d_out (dead before final GEMM writes it);
    // chunk carries (2 MiB) at d_out+100 MiB (also dead until final GEMM write).
    short* xs_bf = (short*)d_out;
    float* blkl  = (float*)((char*)d_out + (size_t)100 * 1024 * 1024);

    cast_kernel<<<SEQ * DIM / 4 / 256, 256, 0, stream>>>(xs, xs_bf, SEQ * DIM / 4);
    cast_kernel<<<DIM * DIM / 4 / 256, 256, 0, stream>>>(w_in, w_bf, DIM * DIM / 4);
    cast_kernel<<<DIM * DIM / 4 / 256, 256, 0, stream>>>(c_out, c_bf, DIM * DIM / 4);

    dim3 ggrid(DIM / 256, SEQ / 256);   // (8, 64): x==8 matches XCD round-robin
    gemm_bt<0><<<ggrid, 512, 0, stream>>>(xs_bf, w_bf, bxh, nullptr, nullptr, nullptr);

    dim3 sgrid(DIM / 1024, NCHUNK);     // (2, 256)
    scan_pass1<<<sgrid, 256, 0, stream>>>(bxh, lam, blkl);
    scan_pass2<<<DIM / 256, 256, 0, stream>>>(blkl, lam);
    scan_pass3<<<sgrid, 256, 0, stream>>>(bxh, lam, blkl);

    gemm_bt<1><<<ggrid, 512, 0, stream>>>(bxh, c_bf, nullptr, out, xs, dskip);
}

// Round 5
// 551.361 us; speedup vs baseline: 1.1657x; 1.1657x over previous
//
#include <hip/hip_runtime.h>

#define SEQ   16384
#define DIM   2048
#define CHUNK 128
#define NCHUNK (SEQ / CHUNK)   // 128

typedef __attribute__((ext_vector_type(8))) short  short8;
typedef __attribute__((ext_vector_type(4))) short  short4v;
typedef __attribute__((ext_vector_type(4))) float  floatx4;

static __device__ __forceinline__ float bf2f(short s) {
    return __uint_as_float(((unsigned)(unsigned short)s) << 16);
}
static __device__ __forceinline__ short f2bf(float f) {
    unsigned u = __float_as_uint(f);
    u += 0x7fff + ((u >> 16) & 1);   // RNE
    return (short)(u >> 16);
}

// ---------- fp32 -> bf16 cast, float4 vectorized ----------
__global__ void cast_kernel(const float* __restrict__ in, short* __restrict__ out, int n4) {
    int i = blockIdx.x * blockDim.x + threadIdx.x;
    if (i >= n4) return;
    float4 v = ((const float4*)in)[i];
    short4v s;
    s.x = f2bf(v.x); s.y = f2bf(v.y); s.z = f2bf(v.z); s.w = f2bf(v.w);
    ((short4v*)out)[i] = s;
}

// ---------- bf16 GEMM, C[m][n] = sum_k A[m][k]*B[n][k] (both K-contiguous) ----------
// 256x256 tile, BK=64, 512 threads = 8 waves (2M x 4N), wave => 128x64 output.
// REGISTER-PIPELINED 8-phase schedule (R3 structure, best measured) + XCD-CHUNK
// SWIZZLE: raw block id -> (xcd = raw&7 owns an 8-row x 8-col super-tile of the
// 8x64 block grid). Each A-panel is then fetched by exactly ONE XCD (was 8),
// and the 32 resident blocks per XCD share 4 A-panels (4 MB, L2-fit) x 8
// B-panels. Targets the measured 5x over-fetch (FETCH 350 MB vs 72 MB unique).
// FUSE==0: store bf16 C. FUSE==1: store fp32 C + xs*dskip.

#define BAR   __builtin_amdgcn_s_barrier()
#define PRIO1 __builtin_amdgcn_s_setprio(1)
#define PRIO0 __builtin_amdgcn_s_setprio(0)
#define LGKM0 asm volatile("s_waitcnt lgkmcnt(0)" ::: "memory")
#define VMC4  asm volatile("s_waitcnt vmcnt(4)" ::: "memory")
#define VMC0  asm volatile("s_waitcnt vmcnt(0)" ::: "memory")

// stage one 128x64 half-tile (16 KiB): 2 x global_load_lds(16B) per thread.
// LDS dest linear; global source slot XOR-swizzled (involution s^(row&7)) so the
// swizzled ds_read sees logical data. Bank-conflict-free (verified 0).
#define STAGE_A(b, h, t) do { \
    const short* _s = Abase + (size_t)(h) * 128 * K + (size_t)(t) * 64; \
    __builtin_amdgcn_global_load_lds(_s + gOff0, &As[b][h][c0 * 8], 16, 0, 0); \
    __builtin_amdgcn_global_load_lds(_s + gOff1, &As[b][h][c1 * 8], 16, 0, 0); \
} while (0)
#define STAGE_B(b, h, t) do { \
    const short* _s = Bbase + (size_t)(h) * 128 * K + (size_t)(t) * 64; \
    __builtin_amdgcn_global_load_lds(_s + gOff0, &Bs[b][h][c0 * 8], 16, 0, 0); \
    __builtin_amdgcn_global_load_lds(_s + gOff1, &Bs[b][h][c1 * 8], 16, 0, 0); \
} while (0)

// fragment reads: logical slot (ks*4+quad), physical slot XOR (row&7) = sx
#define LDA_(dst, b, mh) \
    _Pragma("unroll") \
    for (int mi = 0; mi < 4; mi++) { \
        _Pragma("unroll") \
        for (int ks = 0; ks < 2; ks++) \
            dst[mi][ks] = *(const short8*)&As[b][mh][(arow + mi * 16) * 64 + \
                                                     ((((ks << 2) | quad) ^ sx) << 3)]; \
    }
#define LDB_(dst, b, nh) \
    _Pragma("unroll") \
    for (int ni = 0; ni < 2; ni++) { \
        _Pragma("unroll") \
        for (int ks = 0; ks < 2; ks++) \
            dst[ni][ks] = *(const short8*)&Bs[b][nh][(brow + ni * 16) * 64 + \
                                                     ((((ks << 2) | quad) ^ sx) << 3)]; \
    }
#define MMA(mh, nh, Aset, Bset) \
    _Pragma("unroll") \
    for (int mi = 0; mi < 4; mi++) { \
        _Pragma("unroll") \
        for (int ni = 0; ni < 2; ni++) { \
            acc[mh][nh][mi][ni] = __builtin_amdgcn_mfma_f32_16x16x32_bf16( \
                Aset[mi][0], Bset[ni][0], acc[mh][nh][mi][ni], 0, 0, 0); \
            acc[mh][nh][mi][ni] = __builtin_amdgcn_mfma_f32_16x16x32_bf16( \
                Aset[mi][1], Bset[ni][1], acc[mh][nh][mi][ni], 0, 0, 0); \
        } \
    }

template<int FUSE>
__global__ __launch_bounds__(512, 2)
void gemm_bt(const short* __restrict__ A, const short* __restrict__ B,
             short* __restrict__ Cbf, float* __restrict__ Cf,
             const float* __restrict__ xs, const float* __restrict__ dskip)
{
    constexpr int K  = DIM;        // 2048
    constexpr int NT = K / 64;     // 32 K-tiles

    __shared__ alignas(16) short As[2][2][128 * 64];   // [buf][half][row*64+slot*8]
    __shared__ alignas(16) short Bs[2][2][128 * 64];

    const int tid = threadIdx.x;
    // XCD-chunk swizzle (bijective on the 8x64 grid): hw xcd = raw%8 owns an
    // 8x8 super-tile (rows 8*xcd..8*xcd+7, all 8 cols), x-fastest within.
    const int raw  = blockIdx.y * gridDim.x + blockIdx.x;
    const int xcd  = raw & 7;
    const int slot = raw >> 3;                 // 0..63
    const int m0   = ((xcd << 3) | (slot >> 3)) * 256;
    const int n0   = (slot & 7) * 256;

    const int lane = tid & 63;
    const int wv   = tid >> 6;
    const int wrow = wv >> 2;           // 0..1
    const int wcol = wv & 3;            // 0..3
    const int l16  = lane & 15;
    const int quad = lane >> 4;
    const int sx   = l16 & 7;
    const int arow = wrow * 64 + l16;   // local row in A half-region (strided map)
    const int brow = wcol * 32 + l16;   // local row in B half-region

    // staging constants: chunks c0, c1 of each half-tile (1024 x 16B chunks)
    const int c0 = tid, c1 = tid + 512;
    const int r0 = c0 >> 3, r1 = c1 >> 3;
    const size_t gOff0 = (size_t)r0 * K + (size_t)((((c0 & 7) ^ (r0 & 7))) * 8);
    const size_t gOff1 = (size_t)r1 * K + (size_t)((((c1 & 7) ^ (r1 & 7))) * 8);
    const short* Abase = A + (size_t)m0 * K;
    const short* Bbase = B + (size_t)n0 * K;

    short8  A0[4][2], A1[4][2], B0[2][2], B1[2][2];
    floatx4 acc[2][2][4][2] = {};   // [mh][nh][mi][ni]

    // ---- prologue: tile0 -> buf0 (8 loads), tile1 {Ah0,Bh0} -> buf1 (4 loads)
    STAGE_A(0, 0, 0); STAGE_B(0, 0, 0); STAGE_A(0, 1, 0); STAGE_B(0, 1, 0);
    STAGE_A(1, 0, 1); STAGE_B(1, 0, 1);
    VMC4;           // tile0 fully staged (<=4 outstanding = tile1's)
    BAR;
    LDA_(A0, 0, 0); LDB_(B0, 0, 0);          // prefetch tile0's first quadrant operands
    STAGE_A(1, 1, 1); STAGE_B(1, 1, 1);      // tile1 {Ah1,Bh1}; outstanding <= 8

    for (int i = 0; i < NT / 2; ++i) {
        const int tE = (2 * i + 2) & (NT - 1);   // staged during even tile -> buf0
        const int tO = (2 * i + 3) & (NT - 1);   // staged during odd tile  -> buf1

        // ================= tile even (buf0) =================
        // P1: mma(A0,B0); read B1,A1 from buf0; stage buf0.Ah0 <- tE
        LGKM0;                                   // drains prev P7/prologue prefetch (stale)
        STAGE_A(0, 0, tE);
        LDB_(B1, 0, 1); LDA_(A1, 0, 1);
        PRIO1; MMA(0, 0, A0, B0); PRIO0;
        BAR;
        // P2: mma(A0,B1); stage buf0.Bh0 <- tE
        STAGE_B(0, 0, tE);
        PRIO1; MMA(0, 1, A0, B1); PRIO0;
        BAR;
        // P3: mma(A1,B0); then prefetch next tile's A0,B0 from buf1 (ready per VMC4)
        LGKM0;                                   // drains P1 reads before Ah1 restage
        VMC4;                                    // buf1 (tile 2i+1) fully staged
        STAGE_A(0, 1, tE);
        PRIO1; MMA(1, 0, A1, B0); PRIO0;
        LDA_(A0, 1, 0); LDB_(B0, 1, 0);
        BAR;
        // P4: mma(A1,B1); stage buf0.Bh1 <- tE
        STAGE_B(0, 1, tE);
        PRIO1; MMA(1, 1, A1, B1); PRIO0;
        BAR;

        // ================= tile odd (buf1) =================
        // P5: mma(A0,B0); read B1,A1 from buf1; stage buf1.Ah0 <- tO
        LGKM0;                                   // drains P3 prefetch before Ah0 restage
        STAGE_A(1, 0, tO);
        LDB_(B1, 1, 1); LDA_(A1, 1, 1);
        PRIO1; MMA(0, 0, A0, B0); PRIO0;
        BAR;
        // P6: mma(A0,B1); stage buf1.Bh0 <- tO
        STAGE_B(1, 0, tO);
        PRIO1; MMA(0, 1, A0, B1); PRIO0;
        BAR;
        // P7: mma(A1,B0); prefetch next-even tile's A0,B0 from buf0
        LGKM0;                                   // drains P5 reads before Ah1 restage
        VMC4;                                    // buf0 (tile 2i+2) fully staged
        STAGE_A(1, 1, tO);
        PRIO1; MMA(1, 0, A1, B0); PRIO0;
        LDA_(A0, 0, 0); LDB_(B0, 0, 0);
        BAR;
        // P8: mma(A1,B1); stage buf1.Bh1 <- tO
        STAGE_B(1, 1, tO);
        PRIO1; MMA(1, 1, A1, B1); PRIO0;
        BAR;
    }
    VMC0;   // no LDS-DMA may outlive this workgroup

    // ---- epilogue: C row = m0+wrow*64+mh*128+mi*16+quad*4+r, col = n0+wcol*32+nh*128+ni*16+l16
    if (FUSE == 0) {
        #pragma unroll
        for (int mh = 0; mh < 2; mh++)
        #pragma unroll
        for (int mi = 0; mi < 4; mi++) {
            const int rb = m0 + wrow * 64 + mh * 128 + mi * 16 + quad * 4;
            #pragma unroll
            for (int nh = 0; nh < 2; nh++)
            #pragma unroll
            for (int ni = 0; ni < 2; ni++) {
                const int cc = n0 + wcol * 32 + nh * 128 + ni * 16 + l16;
                #pragma unroll
                for (int r = 0; r < 4; r++)
                    Cbf[(size_t)(rb + r) * DIM + cc] = f2bf(acc[mh][nh][mi][ni][r]);
            }
        }
    } else {
        float dsk[2][2];
        #pragma unroll
        for (int nh = 0; nh < 2; nh++)
        #pragma unroll
        for (int ni = 0; ni < 2; ni++)
            dsk[nh][ni] = dskip[n0 + wcol * 32 + nh * 128 + ni * 16 + l16];
        #pragma unroll
        for (int mh = 0; mh < 2; mh++)
        #pragma unroll
        for (int mi = 0; mi < 4; mi++) {
            const int rb = m0 + wrow * 64 + mh * 128 + mi * 16 + quad * 4;
            #pragma unroll
            for (int nh = 0; nh < 2; nh++)
            #pragma unroll
            for (int ni = 0; ni < 2; ni++) {
                const int cc = n0 + wcol * 32 + nh * 128 + ni * 16 + l16;
                #pragma unroll
                for (int r = 0; r < 4; r++) {
                    size_t idx = (size_t)(rb + r) * DIM + cc;
                    Cf[idx] = acc[mh][nh][mi][ni][r] + xs[idx] * dsk[nh][ni];
                }
            }
        }
    }
}

// ---------- scan pass 1: per-chunk local final state (zero init), 4 cols/thread ----------
__global__ void scan_pass1(const short* __restrict__ bx, const float* __restrict__ lam,
                           float* __restrict__ blockLast)
{
    int q     = blockIdx.x * 256 + threadIdx.x;   // 4-col group id, q < DIM/4
    int n     = q * 4;
    int chunk = blockIdx.y;
    float4 lm = *(const float4*)&lam[n];
    const uint2* p = (const uint2*)(bx + (size_t)chunk * CHUNK * DIM) + q;
    float h0 = 0.f, h1 = 0.f, h2 = 0.f, h3 = 0.f;
    #pragma unroll 16
    for (int i = 0; i < CHUNK; i++) {
        uint2 v = p[(size_t)i * (DIM / 4)];
        h0 = fmaf(lm.x, h0, bf2f((short)(v.x & 0xffffu)));
        h1 = fmaf(lm.y, h1, bf2f((short)(v.x >> 16)));
        h2 = fmaf(lm.z, h2, bf2f((short)(v.y & 0xffffu)));
        h3 = fmaf(lm.w, h3, bf2f((short)(v.y >> 16)));
    }
    float4 o; o.x = h0; o.y = h1; o.z = h2; o.w = h3;
    *(float4*)&blockLast[(size_t)chunk * DIM + n] = o;
}

// ---------- scan pass 2: exclusive prefix over chunks (in place), 1 col/thread ----------
__global__ void scan_pass2(float* __restrict__ blockLast, const float* __restrict__ lam)
{
    int n = blockIdx.x * 256 + threadIdx.x;
    float lm = lam[n];
    float p = lm;
    #pragma unroll
    for (int i = 0; i < 7; i++) p = p * p;    // lam^128
    float carry = 0.f;
    #pragma unroll 4
    for (int c = 0; c < NCHUNK; c++) {
        float t = blockLast[(size_t)c * DIM + n];
        blockLast[(size_t)c * DIM + n] = carry;
        carry = fmaf(p, carry, t);
    }
}

// ---------- scan pass 3: apply carry, write hs (bf16, in place over bx), 4 cols/thread ----------
__global__ void scan_pass3(short* __restrict__ bxh, const float* __restrict__ lam,
                           const float* __restrict__ carry)
{
    int q     = blockIdx.x * 256 + threadIdx.x;
    int n     = q * 4;
    int chunk = blockIdx.y;
    float4 lm = *(const float4*)&lam[n];
    float4 cv = *(const float4*)&carry[(size_t)chunk * DIM + n];
    float h0 = cv.x, h1 = cv.y, h2 = cv.z, h3 = cv.w;
    uint2* p = (uint2*)(bxh + (size_t)chunk * CHUNK * DIM) + q;
    #pragma unroll 16
    for (int i = 0; i < CHUNK; i++) {
        uint2 v = p[(size_t)i * (DIM / 4)];
        h0 = fmaf(lm.x, h0, bf2f((short)(v.x & 0xffffu)));
        h1 = fmaf(lm.y, h1, bf2f((short)(v.x >> 16)));
        h2 = fmaf(lm.z, h2, bf2f((short)(v.y & 0xffffu)));
        h3 = fmaf(lm.w, h3, bf2f((short)(v.y >> 16)));
        uint2 o;
        o.x = (unsigned)(unsigned short)f2bf(h0) | ((unsigned)(unsigned short)f2bf(h1) << 16);
        o.y = (unsigned)(unsigned short)f2bf(h2) | ((unsigned)(unsigned short)f2bf(h3) << 16);
        p[(size_t)i * (DIM / 4)] = o;
    }
}

extern "C" void kernel_launch(void* const* d_in, const int* in_sizes, int n_in,
                              void* d_out, int out_size, void* d_ws, size_t ws_size,
                              hipStream_t stream)
{
    const float* xs    = (const float*)d_in[0];
    const float* lam   = (const float*)d_in[1];
    const float* w_in  = (const float*)d_in[2];
    const float* c_out = (const float*)d_in[3];
    const float* dskip = (const float*)d_in[4];
    float* out = (float*)d_out;

    // ws layout:
    //   [0,   64M) : bx / hs  bf16  [SEQ][DIM]
    //   [64M, 72M) : w_in     bf16  [DIM][DIM]
    //   [72M, 80M) : c_out    bf16  [DIM][DIM]
    char*  ws    = (char*)d_ws;
    short* bxh   = (short*)ws;
    short* w_bf  = (short*)(ws + (size_t)64 * 1024 * 1024);
    short* c_bf  = (short*)(ws + (size_t)72 * 1024 * 1024);
    // xs_bf16 in front 64 MiB of d_out (dead before final GEMM writes it);
    // chunk carries (1 MiB) at d_out+100 MiB (also dead until final GEMM write).
    short* xs_bf = (short*)d_out;
    float* blkl  = (float*)((char*)d_out + (size_t)100 * 1024 * 1024);

    cast_kernel<<<SEQ * DIM / 4 / 256, 256, 0, stream>>>(xs, xs_bf, SEQ * DIM / 4);
    cast_kernel<<<DIM * DIM / 4 / 256, 256, 0, stream>>>(w_in, w_bf, DIM * DIM / 4);
    cast_kernel<<<DIM * DIM / 4 / 256, 256, 0, stream>>>(c_out, c_bf, DIM * DIM / 4);

    dim3 ggrid(DIM / 256, SEQ / 256);   // (8, 64)
    gemm_bt<0><<<ggrid, 512, 0, stream>>>(xs_bf, w_bf, bxh, nullptr, nullptr, nullptr);

    dim3 sgrid(DIM / 1024, NCHUNK);     // (2, 128)
    scan_pass1<<<sgrid, 256, 0, stream>>>(bxh, lam, blkl);
    scan_pass2<<<DIM / 256, 256, 0, stream>>>(blkl, lam);
    scan_pass3<<<sgrid, 256, 0, stream>>>(bxh, lam, blkl);

    gemm_bt<1><<<ggrid, 512, 0, stream>>>(bxh, c_bf, nullptr, out, xs, dskip);
}